// Round 15
// baseline (10770.837 us; speedup 1.0000x reference)
//
#include <hip/hip_runtime.h>
#include <cstddef>
#include <cstdint>

#define NB 32     // batch
#define HD 512    // hidden
#define GD 2048   // 4*hidden
#define NL0 32    // layer-0 blocks (16 hidden each)
#define NL1 32    // layer-1 blocks (16 hidden each)
#define NGB 192   // fused gemm blocks (bid 64..255)
#define FSTR 64   // u32 stride between flags (256 B each)
#define NSLOT 8   // ring slots
#define LOSC 0.00048828125f   // 1/2048

typedef unsigned short u16;
typedef unsigned int u32;
typedef unsigned long long u64;
typedef _Float16 f16;
typedef __attribute__((ext_vector_type(8))) _Float16 f16x8;
typedef __attribute__((ext_vector_type(4))) float f32x4;

#define MFMAF(a, b, c) __builtin_amdgcn_mfma_f32_16x16x32_f16((a), (b), (c), 0, 0, 0)
#define AT_LD(p)   __hip_atomic_load((p), __ATOMIC_RELAXED, __HIP_MEMORY_SCOPE_AGENT)

#define LDG16(dst, p) \
    asm volatile("global_load_dwordx4 %0, %1, off sc0 sc1" : "=&v"(dst) : "v"(p))
#define ST8(p, v) \
    asm volatile("global_store_dwordx2 %0, %1, off sc0 sc1" :: "v"(p), "v"(v) : "memory")
#define VMCNT0() asm volatile("s_waitcnt vmcnt(0)" ::: "memory")
#define SBAR()   __builtin_amdgcn_sched_barrier(0)

__device__ __forceinline__ float sigf(float x)   { return 1.0f / (1.0f + __expf(-x)); }
__device__ __forceinline__ float tanhf_(float x) { return 2.0f / (1.0f + __expf(-2.0f * x)) - 1.0f; }

__device__ __forceinline__ u16 f2h_bits(float x) {
    f16 h = (f16)x; union { f16 f; u16 u; } c; c.f = h; return c.u;
}
__device__ __forceinline__ float h2f(u16 b) {
    union { u16 u; f16 f; } c; c.u = b; return (float)c.f;
}

// split 8 fp32 -> f16 hi + f16 lo*2048
__device__ __forceinline__ void split8f(const float4 a, const float4 b, f16x8& hi, f16x8& lo) {
    float v[8] = {a.x, a.y, a.z, a.w, b.x, b.y, b.z, b.w};
#pragma unroll
    for (int q = 0; q < 8; ++q) {
        const f16 h = (f16)v[q];
        hi[q] = h;
        lo[q] = (f16)((v[q] - (float)h) * 2048.0f);
    }
}
__device__ __forceinline__ void cvt8(const float4 a, const float4 b, f16x8& o) {
    o[0] = (f16)a.x; o[1] = (f16)a.y; o[2] = (f16)a.z; o[3] = (f16)a.w;
    o[4] = (f16)b.x; o[5] = (f16)b.y; o[6] = (f16)b.z; o[7] = (f16)b.w;
}

__global__ __launch_bounds__(256) void wsplit_kernel(
    const float* __restrict__ src, u16* __restrict__ hi, u16* __restrict__ lo, int n)
{
    const int i = blockIdx.x * 256 + threadIdx.x;
    if (i < n) {
        const float x = src[i];
        const f16 h = (f16)x;
        union { f16 f; u16 u; } c; c.f = h;
        hi[i] = c.u;
        lo[i] = f2h_bits((x - (float)h) * 2048.0f);
    }
}

__global__ __launch_bounds__(256) void cvtf_kernel(
    const float* __restrict__ src, u16* __restrict__ dst, int n)
{
    const int i = blockIdx.x * 256 + threadIdx.x;
    if (i < n) dst[i] = f2h_bits(src[i]);
}

__global__ __launch_bounds__(256) void addv_kernel(
    const float* __restrict__ a, const float* __restrict__ b, float* __restrict__ o, int n)
{
    const int i = blockIdx.x * 256 + threadIdx.x;
    if (i < n) o[i] = a[i] + b[i];
}

// f16-split MFMA GEMM, C tile 64x64, K=512 (standalone; unchanged).
template<int MODE>
__global__ __launch_bounds__(256) void mfma_gemm(
    const float* __restrict__ A, int T, int t0, int tc_bits,
    const float* __restrict__ W, int N,
    const float* __restrict__ b1, const float* __restrict__ b2x,
    float* __restrict__ out, int t_bits, int u_bits)
{
    __shared__ __align__(16) u16 As[64][40], Bh[64][40], Bl[64][40];
    const int tid = threadIdx.x;
    const int m0 = blockIdx.x << 6, n0 = blockIdx.y << 6;

    const int ar = tid >> 2, aks = (tid & 3) << 3;
    const float* aPtr;
    if (MODE == 0) {
        const int rg = m0 + ar;
        const int b = rg >> tc_bits;
        const int tt = t0 + (rg & ((1 << tc_bits) - 1));
        aPtr = A + (((size_t)b * T + tt) << 9) + aks;
    } else {
        aPtr = A + (((size_t)(m0 + ar)) << 9) + aks;
    }
    const float* bPtr = nullptr;
    int bkk = 0, bns = 0;
    if (MODE == 0) {
        bPtr = W + (((size_t)(n0 + ar)) << 9) + aks;
    } else {
        bkk = tid >> 3; bns = (tid & 7) << 3;
        bPtr = W + (size_t)bkk * N + n0 + bns;
    }

    const int lane = tid & 63, wv = tid >> 6;
    const int fr = lane & 15, ko = (lane >> 4) << 3;
    f32x4 acc[4] = {}, accl[4] = {};

    for (int k0 = 0; k0 < HD; k0 += 32) {
        {
            const float4 a1 = *(const float4*)(aPtr + k0);
            const float4 a2 = *(const float4*)(aPtr + k0 + 4);
            f16x8 av; cvt8(a1, a2, av);
            *(f16x8*)&As[ar][aks] = av;
        }
        if (MODE == 0) {
            const float4 w1 = *(const float4*)(bPtr + k0);
            const float4 w2 = *(const float4*)(bPtr + k0 + 4);
            f16x8 vh, vl; split8f(w1, w2, vh, vl);
            *(f16x8*)&Bh[ar][aks] = vh;
            *(f16x8*)&Bl[ar][aks] = vl;
        } else {
            const float4 w1 = *(const float4*)(bPtr + (size_t)k0 * N);
            const float4 w2 = *(const float4*)(bPtr + (size_t)k0 * N + 4);
            f16x8 vh, vl; split8f(w1, w2, vh, vl);
#pragma unroll
            for (int q = 0; q < 8; ++q) {
                union { f16 f; u16 u; } ch, cl; ch.f = vh[q]; cl.f = vl[q];
                Bh[bns + q][bkk] = ch.u;
                Bl[bns + q][bkk] = cl.u;
            }
        }
        __syncthreads();
        const f16x8 ahf = *(const f16x8*)&As[(wv << 4) + fr][ko];
#pragma unroll
        for (int nt = 0; nt < 4; ++nt) {
            const f16x8 bhf = *(const f16x8*)&Bh[(nt << 4) + fr][ko];
            const f16x8 blf = *(const f16x8*)&Bl[(nt << 4) + fr][ko];
            acc[nt]  = MFMAF(ahf, bhf, acc[nt]);
            accl[nt] = MFMAF(ahf, blf, accl[nt]);
        }
        __syncthreads();
    }

    const int mlb = (wv << 4) + ((lane >> 4) << 2);
#pragma unroll
    for (int r = 0; r < 4; ++r) {
        const int mg = m0 + mlb + r;
#pragma unroll
        for (int nt = 0; nt < 4; ++nt) {
            const int n = n0 + (nt << 4) + fr;
            const float v = acc[nt][r] + accl[nt][r] * LOSC;
            if (MODE == 0) {
                out[((size_t)mg << 11) + n] = v + b1[n] + b2x[n];
            } else {
                const int bb = mg >> t_bits, tt = mg & ((1 << t_bits) - 1);
                const int uu = n >> 9, hh = n & 511;
                const size_t di = (((size_t)((((bb << t_bits) + tt) << u_bits) + uu)) << 9) + hh;
                out[di] = v + b1[n] + b2x[di];
            }
        }
    }
}

// ---------------- persistent fused scan + next-chunk GEMM ----------------
// 256 blocks x 512 threads. [0,32): layer0 (16 hidden); [32,64): layer1
// (16 hidden, dual matrices — halves l1's coherent ring traffic vs 64-block
// variant). [64,256): grid-stride xg GEMM for the NEXT chunk; ntiles==0 -> exit.
//   l0@jj: flags0 >= jj, flags1 >= jj-6   |   l1@jj: flags0 >= jj, flags1 >= jj

#define SPIN_WAIT(TGT0, TGT1) do { \
    if (tid < NL0 + NL1) { \
        const int tgt_ = (tid < NL0) ? (TGT0) : (TGT1); \
        if (tgt_ > 0) { \
            const u32* fp_ = flags + tid * FSTR; \
            int g_ = 0; \
            while ((int)AT_LD(fp_) < tgt_ && ++g_ < (1 << 24)) {} \
        } \
    } \
    SBAR(); \
    __syncthreads(); \
} while (0)

__global__ __launch_bounds__(512, 1) void lstm_scan8g(
    const float* __restrict__ xg, int Tc,
    const u16* __restrict__ w0h,
    const u16* __restrict__ w1ih_h,
    const u16* __restrict__ w1hh_h,
    const float* __restrict__ bsum1,
    u16* __restrict__ r0, u16* __restrict__ r1,
    float* __restrict__ c0ws, float* __restrict__ c1ws,
    float* __restrict__ out1, int T, int t0, int NS,
    u32* __restrict__ flags,
    const float* __restrict__ gA, int gt0, int gtc_bits,
    const float* __restrict__ gW,
    const float* __restrict__ gb1, const float* __restrict__ gb2x,
    float* __restrict__ gxg, int ntiles, int mtiles)
{
    __shared__ __align__(16) float sred[16 * 32 * 20]; // 40 KB
    __shared__ u16 spk[16][33];
    __shared__ __align__(16) u16 gAs[64][40], gBh[64][40], gBl[64][40]; // 15 KB
    const int tid = threadIdx.x;
    const int bid = blockIdx.x;
    const int lane = tid & 63, wv = tid >> 6;
    const int kq = wv >> 1, bh = wv & 1;
    const int fr = lane & 15, kg = lane >> 4;
    const int batch = (bh << 4) + fr;
    const int eb = tid & 31;
    const u32 bko = ((u32)batch << 9) + (kq << 7) + (kg << 3);

    if (bid < NL0) {
        // ================= layer 0: 16 hidden =================
        const int j0 = bid << 4;
        f16x8 Ah_[16];
#pragma unroll
        for (int hq = 0; hq < 4; ++hq) {
            const size_t grow = (((size_t)(fr & 3)) << 9) + j0 + (hq << 2) + (fr >> 2);
#pragma unroll
            for (int ck = 0; ck < 4; ++ck)
                Ah_[(hq << 2) | ck] = *(const f16x8*)(
                    w0h + (grow << 9) + (kq << 7) + (ck << 5) + (kg << 3));
        }
        const int eh = tid >> 5;
        const int hidden = j0 + eh;
        float c_reg = c0ws[((size_t)eb << 9) + hidden];
        __syncthreads();

        for (int jj = 0; jj < Tc; ++jj) {
            const int t = t0 + jj;
            float xv[4];
#pragma unroll
            for (int g = 0; g < 4; ++g)
                xv[g] = xg[(((size_t)eb * Tc + jj) << 11) + (g << 9) + hidden];
            SPIN_WAIT(jj, jj - 6);
            const u16* bp = r0 + (((size_t)((t - 1) & 7)) << 14) + bko;
            f16x8 vb[4];
#pragma unroll
            for (int ck = 0; ck < 4; ++ck)
                LDG16(vb[ck], bp + (ck << 5));
            f32x4 s0[4] = {};
            VMCNT0(); SBAR();
#pragma unroll
            for (int hq = 0; hq < 4; ++hq)
#pragma unroll
                for (int ck = 0; ck < 4; ++ck)
                    s0[hq] = MFMAF(Ah_[(hq << 2) | ck], vb[ck], s0[hq]);
#pragma unroll
            for (int hq = 0; hq < 4; ++hq) {
                const int h16 = (hq << 2) + kg;
                *(f32x4*)&sred[((h16 << 5) + batch) * 20 + (kq << 2)] = s0[hq];
            }
            __syncthreads();
            {
                const int base = ((eh << 5) + eb) * 20;
                const f32x4 q0 = *(const f32x4*)&sred[base];
                const f32x4 q1 = *(const f32x4*)&sred[base + 4];
                const f32x4 q2 = *(const f32x4*)&sred[base + 8];
                const f32x4 q3 = *(const f32x4*)&sred[base + 12];
                const float gi = q0[0] + q1[0] + q2[0] + q3[0] + xv[0];
                const float gf = q0[1] + q1[1] + q2[1] + q3[1] + xv[1];
                const float gg = q0[2] + q1[2] + q2[2] + q3[2] + xv[2];
                const float go = q0[3] + q1[3] + q2[3] + q3[3] + xv[3];
                c_reg = sigf(gf) * c_reg + sigf(gi) * tanhf_(gg);
                const float h = sigf(go) * tanhf_(c_reg);
                spk[eh][eb] = f2h_bits(h);
            }
            __syncthreads();
            if (tid < 128) {
                const int bt = tid & 31, h4 = (tid >> 5) << 2;
                const u64 hp = (u64)spk[h4 + 0][bt] | ((u64)spk[h4 + 1][bt] << 16)
                             | ((u64)spk[h4 + 2][bt] << 32) | ((u64)spk[h4 + 3][bt] << 48);
                const size_t wo = (((size_t)(t & 7)) << 14) + ((size_t)bt << 9) + j0 + h4;
                ST8(r0 + wo, hp);
            }
            VMCNT0();
            __syncthreads();
            if (tid == 0)
                __hip_atomic_store(flags + bid * FSTR, (u32)(jj + 1),
                                   __ATOMIC_RELAXED, __HIP_MEMORY_SCOPE_AGENT);
        }
        c0ws[((size_t)eb << 9) + hidden] = c_reg;
    } else if (bid < NL0 + NL1) {
        // ================= layer 1: 16 hidden, dual matrices =================
        const int j0 = (bid - NL0) << 4;
        f16x8 Ai_[16], Ahh_[16];
#pragma unroll
        for (int hq = 0; hq < 4; ++hq) {
            const size_t grow = (((size_t)(fr & 3)) << 9) + j0 + (hq << 2) + (fr >> 2);
#pragma unroll
            for (int ck = 0; ck < 4; ++ck) {
                const size_t o = (grow << 9) + (kq << 7) + (ck << 5) + (kg << 3);
                Ai_[(hq << 2) | ck]  = *(const f16x8*)(w1ih_h + o);
                Ahh_[(hq << 2) | ck] = *(const f16x8*)(w1hh_h + o);
            }
        }
        const int eh = tid >> 5;
        const int hidden = j0 + eh;
        float bs[4];
#pragma unroll
        for (int g = 0; g < 4; ++g) bs[g] = bsum1[(g << 9) + hidden];
        float c_reg = c1ws[((size_t)eb << 9) + hidden];
        __syncthreads();

        for (int jj = 0; jj < NS; ++jj) {
            const int t = t0 + jj - 1;
            SPIN_WAIT(jj, jj);
            if (t >= 0) {
                const u16* ap = r0 + (((size_t)(t & 7)) << 14) + bko;
                const u16* bp = r1 + (((size_t)((t - 1) & 7)) << 14) + bko;
                f16x8 va[4], vb[4];
#pragma unroll
                for (int ck = 0; ck < 4; ++ck) {
                    LDG16(va[ck], ap + (ck << 5));
                    LDG16(vb[ck], bp + (ck << 5));
                }
                f32x4 s0[4] = {};
                VMCNT0(); SBAR();
#pragma unroll
                for (int hq = 0; hq < 4; ++hq)
#pragma unroll
                    for (int ck = 0; ck < 4; ++ck) {
                        s0[hq] = MFMAF(Ai_[(hq << 2) | ck], va[ck], s0[hq]);
                        s0[hq] = MFMAF(Ahh_[(hq << 2) | ck], vb[ck], s0[hq]);
                    }
#pragma unroll
                for (int hq = 0; hq < 4; ++hq) {
                    const int h16 = (hq << 2) + kg;
                    *(f32x4*)&sred[((h16 << 5) + batch) * 20 + (kq << 2)] = s0[hq];
                }
            }
            __syncthreads();
            if (t >= 0) {
                const int base = ((eh << 5) + eb) * 20;
                const f32x4 q0 = *(const f32x4*)&sred[base];
                const f32x4 q1 = *(const f32x4*)&sred[base + 4];
                const f32x4 q2 = *(const f32x4*)&sred[base + 8];
                const f32x4 q3 = *(const f32x4*)&sred[base + 12];
                const float gi = q0[0] + q1[0] + q2[0] + q3[0] + bs[0];
                const float gf = q0[1] + q1[1] + q2[1] + q3[1] + bs[1];
                const float gg = q0[2] + q1[2] + q2[2] + q3[2] + bs[2];
                const float go = q0[3] + q1[3] + q2[3] + q3[3] + bs[3];
                c_reg = sigf(gf) * c_reg + sigf(gi) * tanhf_(gg);
                const float h = sigf(go) * tanhf_(c_reg);
                spk[eh][eb] = f2h_bits(h);
            }
            __syncthreads();
            if (t >= 0 && tid < 128) {
                const int bt = tid & 31, h4 = (tid >> 5) << 2;
                const u64 hp = (u64)spk[h4 + 0][bt] | ((u64)spk[h4 + 1][bt] << 16)
                             | ((u64)spk[h4 + 2][bt] << 32) | ((u64)spk[h4 + 3][bt] << 48);
                const size_t wo = (((size_t)(t & 7)) << 14) + ((size_t)bt << 9) + j0 + h4;
                ST8(r1 + wo, hp);
            }
            VMCNT0();
            __syncthreads();
            if (tid == 0)
                __hip_atomic_store(flags + bid * FSTR, (u32)(jj + 1),
                                   __ATOMIC_RELAXED, __HIP_MEMORY_SCOPE_AGENT);
            // out1 write AFTER flag — off the critical path.
            if (t >= 0 && tid < 128) {
                const int bt = tid & 31, h4 = (tid >> 5) << 2;
                float4 o;
                o.x = h2f(spk[h4 + 0][bt]);
                o.y = h2f(spk[h4 + 1][bt]);
                o.z = h2f(spk[h4 + 2][bt]);
                o.w = h2f(spk[h4 + 3][bt]);
                *(float4*)(out1 + (((size_t)bt * T + t) << 9) + j0 + h4) = o;
            }
        }
        c1ws[((size_t)eb << 9) + hidden] = c_reg;
    } else {
        // ================= fused next-chunk xg GEMM =================
        const int gb = bid - (NL0 + NL1);
        const int ko = kg << 3;
        for (int tile = gb; tile < ntiles; tile += NGB) {
            const int m0 = (tile % mtiles) << 6;
            const int n0 = (tile / mtiles) << 6;
            const int ar = tid >> 2, aks = (tid & 3) << 3;
            const float* aPtr = nullptr;
            const float* bPtr = nullptr;
            if (tid < 256) {
                const int rg = m0 + ar;
                const int b = rg >> gtc_bits;
                const int tt = gt0 + (rg & ((1 << gtc_bits) - 1));
                aPtr = gA + (((size_t)b * T + tt) << 9) + aks;
                bPtr = gW + (((size_t)(n0 + ar)) << 9) + aks;
            }
            const int wv4 = (tid >> 6) & 3;
            f32x4 acc[4] = {}, accl[4] = {};
            for (int k0 = 0; k0 < HD; k0 += 32) {
                if (tid < 256) {
                    const float4 a1 = *(const float4*)(aPtr + k0);
                    const float4 a2 = *(const float4*)(aPtr + k0 + 4);
                    f16x8 av; cvt8(a1, a2, av);
                    *(f16x8*)&gAs[ar][aks] = av;
                    const float4 w1 = *(const float4*)(bPtr + k0);
                    const float4 w2 = *(const float4*)(bPtr + k0 + 4);
                    f16x8 vh, vl; split8f(w1, w2, vh, vl);
                    *(f16x8*)&gBh[ar][aks] = vh;
                    *(f16x8*)&gBl[ar][aks] = vl;
                }
                __syncthreads();
                if (tid < 256) {
                    const f16x8 ahf = *(const f16x8*)&gAs[(wv4 << 4) + fr][ko];
#pragma unroll
                    for (int nt = 0; nt < 4; ++nt) {
                        const f16x8 bhf = *(const f16x8*)&gBh[(nt << 4) + fr][ko];
                        const f16x8 blf = *(const f16x8*)&gBl[(nt << 4) + fr][ko];
                        acc[nt]  = MFMAF(ahf, bhf, acc[nt]);
                        accl[nt] = MFMAF(ahf, blf, accl[nt]);
                    }
                }
                __syncthreads();
            }
            if (tid < 256) {
                const int mlb = (wv4 << 4) + (kg << 2);
#pragma unroll
                for (int r = 0; r < 4; ++r) {
                    const int mg = m0 + mlb + r;
#pragma unroll
                    for (int nt = 0; nt < 4; ++nt) {
                        const int n = n0 + (nt << 4) + fr;
                        gxg[((size_t)mg << 11) + n] =
                            acc[nt][r] + accl[nt][r] * LOSC + gb1[n] + gb2x[n];
                    }
                }
            }
        }
    }
}

extern "C" void kernel_launch(void* const* d_in, const int* in_sizes, int n_in,
                              void* d_out, int out_size, void* d_ws, size_t ws_size,
                              hipStream_t stream)
{
    const float* x[3]   = {(const float*)d_in[0], (const float*)d_in[1],  (const float*)d_in[2]};
    const float* Wih[3] = {(const float*)d_in[3], (const float*)d_in[9],  (const float*)d_in[15]};
    const float* Whh[3] = {(const float*)d_in[4], (const float*)d_in[10], (const float*)d_in[16]};
    const float* bih[3] = {(const float*)d_in[5], (const float*)d_in[11], (const float*)d_in[17]};
    const float* bhh[3] = {(const float*)d_in[6], (const float*)d_in[12], (const float*)d_in[18]};
    const float* h0[3]  = {(const float*)d_in[7], (const float*)d_in[13], (const float*)d_in[19]};
    const float* c0[3]  = {(const float*)d_in[8], (const float*)d_in[14], (const float*)d_in[20]};
    const float* upW[2] = {(const float*)d_in[21], (const float*)d_in[23]};
    const float* upb[2] = {(const float*)d_in[22], (const float*)d_in[24]};

    float* ws = (float*)d_ws;
    float* bufA  = ws;
    float* bufB  = bufA + (size_t)NB * 256 * HD;
    float* c0ws  = bufB + (size_t)NB * 256 * HD;
    float* c1ws  = c0ws + (size_t)NB * HD;
    float* bsum1 = c1ws + (size_t)NB * HD;
    float* xgA   = bsum1 + GD;

    const size_t head_f = 2 * (size_t)NB * 256 * HD + 2 * (size_t)NB * HD + GD;
    const size_t tail_f = 3 * (size_t)GD * HD + NSLOT * (size_t)NB * HD + 64 * FSTR + 64;
    int Tc_cap = 512;
    while (Tc_cap > 32 && (head_f + 2 * (size_t)NB * Tc_cap * GD + tail_f) * 4 > ws_size)
        Tc_cap >>= 1;

    float* xgB  = xgA + (size_t)NB * Tc_cap * GD;
    u16* w0h    = (u16*)(xgB + (size_t)NB * Tc_cap * GD);
    u16* w0l    = w0h + (size_t)GD * HD;
    u16* w1ih_h = w0l + (size_t)GD * HD;
    u16* w1ih_l = w1ih_h + (size_t)GD * HD;
    u16* w1hh_h = w1ih_l + (size_t)GD * HD;
    u16* w1hh_l = w1hh_h + (size_t)GD * HD;
    u16* r0     = w1hh_l + (size_t)GD * HD;   // NSLOT x 16384 u16 (f16 bits)
    u16* r1     = r0 + NSLOT * (size_t)NB * HD;
    u32* flags  = (u32*)(r1 + NSLOT * (size_t)NB * HD);

    auto tier = [&](const float* in, float* out1, int T, int tr) {
        const float* Wih0L = Wih[tr];
        const float* Whh0L = Whh[tr];
        const float* Wih1L = Wih[tr] + (size_t)GD * HD;
        const float* Whh1L = Whh[tr] + (size_t)GD * HD;

        wsplit_kernel<<<(GD * HD) / 256, 256, 0, stream>>>(Whh0L, w0h, w0l, GD * HD);
        wsplit_kernel<<<(GD * HD) / 256, 256, 0, stream>>>(Wih1L, w1ih_h, w1ih_l, GD * HD);
        wsplit_kernel<<<(GD * HD) / 256, 256, 0, stream>>>(Whh1L, w1hh_h, w1hh_l, GD * HD);
        addv_kernel<<<GD / 256, 256, 0, stream>>>(bih[tr] + GD, bhh[tr] + GD, bsum1, GD);
        cvtf_kernel<<<(NB * HD) / 256, 256, 0, stream>>>(
            h0[tr], r0 + 7 * (size_t)NB * HD, NB * HD);
        cvtf_kernel<<<(NB * HD) / 256, 256, 0, stream>>>(
            h0[tr] + (size_t)NB * HD, r1 + 7 * (size_t)NB * HD, NB * HD);
        hipMemcpyAsync(c0ws, c0[tr], (size_t)NB * HD * sizeof(float),
                       hipMemcpyDeviceToDevice, stream);
        hipMemcpyAsync(c1ws, c0[tr] + (size_t)NB * HD, (size_t)NB * HD * sizeof(float),
                       hipMemcpyDeviceToDevice, stream);

        const int Tc = T < Tc_cap ? T : Tc_cap;
        int tc_bits = 0; while ((1 << tc_bits) < Tc) ++tc_bits;
        const int nchunks = T / Tc;
        const int mtiles = (NB * Tc) / 64;
        float* xgb[2] = {xgA, xgB};

        {   // chunk 0 xg: standalone GEMM
            dim3 g(mtiles, GD / 64);
            mfma_gemm<0><<<g, 256, 0, stream>>>(in, T, 0, tc_bits, Wih0L, GD,
                                                bih[tr], bhh[tr], xgb[0], 0, 0);
        }
        for (int ci = 0; ci < nchunks; ++ci) {
            const int t0 = ci * Tc;
            hipMemsetAsync(flags, 0, 64 * FSTR * sizeof(u32), stream);
            const bool last = (ci == nchunks - 1);
            const int NS = Tc + (last ? 1 : 0);
            const int ntiles = last ? 0 : mtiles * (GD / 64);
            const float* xg_p = xgb[ci & 1]; int Tc_a = Tc;
            const u16 *a0 = w0h, *a2 = w1ih_h, *a4 = w1hh_h;
            const float* bs_p = bsum1;
            u16 *p0 = r0, *p1 = r1;
            float *c0p = c0ws, *c1p = c1ws, *o1 = out1;
            int T_a = T, t0_a = t0, NS_a = NS;
            u32* fl = flags;
            const float* gA = in; int gt0 = t0 + Tc; int gtc = tc_bits;
            const float* gW = Wih0L; const float* g1 = bih[tr]; const float* g2 = bhh[tr];
            float* gx = xgb[(ci + 1) & 1]; int nt_a = ntiles; int mt_a = mtiles;
            void* args[] = {(void*)&xg_p, (void*)&Tc_a,
                            (void*)&a0, (void*)&a2, (void*)&a4,
                            (void*)&bs_p, (void*)&p0, (void*)&p1,
                            (void*)&c0p, (void*)&c1p, (void*)&o1,
                            (void*)&T_a, (void*)&t0_a, (void*)&NS_a, (void*)&fl,
                            (void*)&gA, (void*)&gt0, (void*)&gtc,
                            (void*)&gW, (void*)&g1, (void*)&g2,
                            (void*)&gx, (void*)&nt_a, (void*)&mt_a};
            hipLaunchCooperativeKernel((const void*)lstm_scan8g, dim3(256), dim3(512),
                                       args, 0, stream);
        }
    };

    float* dout = (float*)d_out;

    // Tier 0 (T=128): l1 series -> bufB
    tier(x[0], bufB, 128, 0);
    {   // upsample 0: bufB (B,128,512) -> bufA (B,256,512) + x1
        dim3 g((NB * 128) / 64, 1024 / 64);
        mfma_gemm<1><<<g, 256, 0, stream>>>(bufB, 0, 0, 0, upW[0], 1024,
                                            upb[0], x[1], bufA, 7, 1);
    }
    // Tier 1 (T=256): input bufA, l1 series -> bufB
    tier(bufA, bufB, 256, 1);
    {   // upsample 1: bufB (B,256,512) -> dout (B,2048,512) + x2
        dim3 g((NB * 256) / 64, 4096 / 64);
        mfma_gemm<1><<<g, 256, 0, stream>>>(bufB, 0, 0, 0, upW[1], 4096,
                                            upb[1], x[2], dout, 8, 3);
    }
    // Tier 2 (T=2048): input dout (fused GEMM reads chunk i+1 rows; scan writes
    // chunk i rows — disjoint), l1 -> dout
    tier(dout, dout, 2048, 2);
}

// Round 16
// 10404.021 us; speedup vs baseline: 1.0353x; 1.0353x over previous
//
#include <hip/hip_runtime.h>
#include <cstddef>
#include <cstdint>

#define NB 32     // batch
#define HD 512    // hidden
#define GD 2048   // 4*hidden
#define NL0 32    // layer-0 blocks (16 hidden each)
#define NL1 64    // layer-1 blocks (8 hidden each)
#define NGB 160   // fused gemm blocks (bid 96..255)
#define FSTR 64   // u32 stride between flags (256 B each)
#define NSLOT 8   // ring slots
#define LOSC 0.00048828125f   // 1/2048

typedef unsigned short u16;
typedef unsigned int u32;
typedef unsigned long long u64;
typedef _Float16 f16;
typedef __attribute__((ext_vector_type(8))) _Float16 f16x8;
typedef __attribute__((ext_vector_type(4))) float f32x4;

#define MFMAF(a, b, c) __builtin_amdgcn_mfma_f32_16x16x32_f16((a), (b), (c), 0, 0, 0)
#define AT_LD(p)   __hip_atomic_load((p), __ATOMIC_RELAXED, __HIP_MEMORY_SCOPE_AGENT)

#define LDG16(dst, p) \
    asm volatile("global_load_dwordx4 %0, %1, off sc0 sc1" : "=&v"(dst) : "v"(p))
#define ST8(p, v) \
    asm volatile("global_store_dwordx2 %0, %1, off sc0 sc1" :: "v"(p), "v"(v) : "memory")
#define VMCNT0() asm volatile("s_waitcnt vmcnt(0)" ::: "memory")
#define SBAR()   __builtin_amdgcn_sched_barrier(0)

__device__ __forceinline__ float sigf(float x)   { return 1.0f / (1.0f + __expf(-x)); }
__device__ __forceinline__ float tanhf_(float x) { return 2.0f / (1.0f + __expf(-2.0f * x)) - 1.0f; }

__device__ __forceinline__ u16 f2h_bits(float x) {
    f16 h = (f16)x; union { f16 f; u16 u; } c; c.f = h; return c.u;
}
__device__ __forceinline__ float h2f(u16 b) {
    union { u16 u; f16 f; } c; c.u = b; return (float)c.f;
}

// split 8 fp32 -> f16 hi + f16 lo*2048
__device__ __forceinline__ void split8f(const float4 a, const float4 b, f16x8& hi, f16x8& lo) {
    float v[8] = {a.x, a.y, a.z, a.w, b.x, b.y, b.z, b.w};
#pragma unroll
    for (int q = 0; q < 8; ++q) {
        const f16 h = (f16)v[q];
        hi[q] = h;
        lo[q] = (f16)((v[q] - (float)h) * 2048.0f);
    }
}
__device__ __forceinline__ void cvt8(const float4 a, const float4 b, f16x8& o) {
    o[0] = (f16)a.x; o[1] = (f16)a.y; o[2] = (f16)a.z; o[3] = (f16)a.w;
    o[4] = (f16)b.x; o[5] = (f16)b.y; o[6] = (f16)b.z; o[7] = (f16)b.w;
}

__global__ __launch_bounds__(256) void wsplit_kernel(
    const float* __restrict__ src, u16* __restrict__ hi, u16* __restrict__ lo, int n)
{
    const int i = blockIdx.x * 256 + threadIdx.x;
    if (i < n) {
        const float x = src[i];
        const f16 h = (f16)x;
        union { f16 f; u16 u; } c; c.f = h;
        hi[i] = c.u;
        lo[i] = f2h_bits((x - (float)h) * 2048.0f);
    }
}

__global__ __launch_bounds__(256) void cvtf_kernel(
    const float* __restrict__ src, u16* __restrict__ dst, int n)
{
    const int i = blockIdx.x * 256 + threadIdx.x;
    if (i < n) dst[i] = f2h_bits(src[i]);
}

__global__ __launch_bounds__(256) void addv_kernel(
    const float* __restrict__ a, const float* __restrict__ b, float* __restrict__ o, int n)
{
    const int i = blockIdx.x * 256 + threadIdx.x;
    if (i < n) o[i] = a[i] + b[i];
}

// f16-split MFMA GEMM, C tile 64x64, K=512 (standalone; unchanged).
template<int MODE>
__global__ __launch_bounds__(256) void mfma_gemm(
    const float* __restrict__ A, int T, int t0, int tc_bits,
    const float* __restrict__ W, int N,
    const float* __restrict__ b1, const float* __restrict__ b2x,
    float* __restrict__ out, int t_bits, int u_bits)
{
    __shared__ __align__(16) u16 As[64][40], Bh[64][40], Bl[64][40];
    const int tid = threadIdx.x;
    const int m0 = blockIdx.x << 6, n0 = blockIdx.y << 6;

    const int ar = tid >> 2, aks = (tid & 3) << 3;
    const float* aPtr;
    if (MODE == 0) {
        const int rg = m0 + ar;
        const int b = rg >> tc_bits;
        const int tt = t0 + (rg & ((1 << tc_bits) - 1));
        aPtr = A + (((size_t)b * T + tt) << 9) + aks;
    } else {
        aPtr = A + (((size_t)(m0 + ar)) << 9) + aks;
    }
    const float* bPtr = nullptr;
    int bkk = 0, bns = 0;
    if (MODE == 0) {
        bPtr = W + (((size_t)(n0 + ar)) << 9) + aks;
    } else {
        bkk = tid >> 3; bns = (tid & 7) << 3;
        bPtr = W + (size_t)bkk * N + n0 + bns;
    }

    const int lane = tid & 63, wv = tid >> 6;
    const int fr = lane & 15, ko = (lane >> 4) << 3;
    f32x4 acc[4] = {}, accl[4] = {};

    for (int k0 = 0; k0 < HD; k0 += 32) {
        {
            const float4 a1 = *(const float4*)(aPtr + k0);
            const float4 a2 = *(const float4*)(aPtr + k0 + 4);
            f16x8 av; cvt8(a1, a2, av);
            *(f16x8*)&As[ar][aks] = av;
        }
        if (MODE == 0) {
            const float4 w1 = *(const float4*)(bPtr + k0);
            const float4 w2 = *(const float4*)(bPtr + k0 + 4);
            f16x8 vh, vl; split8f(w1, w2, vh, vl);
            *(f16x8*)&Bh[ar][aks] = vh;
            *(f16x8*)&Bl[ar][aks] = vl;
        } else {
            const float4 w1 = *(const float4*)(bPtr + (size_t)k0 * N);
            const float4 w2 = *(const float4*)(bPtr + (size_t)k0 * N + 4);
            f16x8 vh, vl; split8f(w1, w2, vh, vl);
#pragma unroll
            for (int q = 0; q < 8; ++q) {
                union { f16 f; u16 u; } ch, cl; ch.f = vh[q]; cl.f = vl[q];
                Bh[bns + q][bkk] = ch.u;
                Bl[bns + q][bkk] = cl.u;
            }
        }
        __syncthreads();
        const f16x8 ahf = *(const f16x8*)&As[(wv << 4) + fr][ko];
#pragma unroll
        for (int nt = 0; nt < 4; ++nt) {
            const f16x8 bhf = *(const f16x8*)&Bh[(nt << 4) + fr][ko];
            const f16x8 blf = *(const f16x8*)&Bl[(nt << 4) + fr][ko];
            acc[nt]  = MFMAF(ahf, bhf, acc[nt]);
            accl[nt] = MFMAF(ahf, blf, accl[nt]);
        }
        __syncthreads();
    }

    const int mlb = (wv << 4) + ((lane >> 4) << 2);
#pragma unroll
    for (int r = 0; r < 4; ++r) {
        const int mg = m0 + mlb + r;
#pragma unroll
        for (int nt = 0; nt < 4; ++nt) {
            const int n = n0 + (nt << 4) + fr;
            const float v = acc[nt][r] + accl[nt][r] * LOSC;
            if (MODE == 0) {
                out[((size_t)mg << 11) + n] = v + b1[n] + b2x[n];
            } else {
                const int bb = mg >> t_bits, tt = mg & ((1 << t_bits) - 1);
                const int uu = n >> 9, hh = n & 511;
                const size_t di = (((size_t)((((bb << t_bits) + tt) << u_bits) + uu)) << 9) + hh;
                out[di] = v + b1[n] + b2x[di];
            }
        }
    }
}

// ---------------- persistent fused scan + next-chunk GEMM (round-14 best) ----
// 256 blocks x 512 threads. [0,32): layer0; [32,96): layer1 (8 hidden).
// [96,256): grid-stride xg GEMM for the NEXT chunk; ntiles==0 -> exit.
//   l0@jj: flags0 >= jj, flags1 >= jj-6   |   l1@jj: flags0 >= jj, flags1 >= jj

#define SPIN_WAIT(TGT0, TGT1) do { \
    if (tid < NL0 + NL1) { \
        const int tgt_ = (tid < NL0) ? (TGT0) : (TGT1); \
        if (tgt_ > 0) { \
            const u32* fp_ = flags + tid * FSTR; \
            int g_ = 0; \
            while ((int)AT_LD(fp_) < tgt_ && ++g_ < (1 << 24)) {} \
        } \
    } \
    SBAR(); \
    __syncthreads(); \
} while (0)

__global__ __launch_bounds__(512, 2) void lstm_scan8f(
    const float* __restrict__ xg, int Tc,
    const u16* __restrict__ w0h,
    const u16* __restrict__ w1ih_h,
    const u16* __restrict__ w1hh_h,
    const float* __restrict__ bsum1,
    u16* __restrict__ r0, u16* __restrict__ r1,
    float* __restrict__ c0ws, float* __restrict__ c1ws,
    float* __restrict__ out1, int T, int t0, int NS,
    u32* __restrict__ flags,
    const float* __restrict__ gA, int gt0, int gtc_bits,
    const float* __restrict__ gW,
    const float* __restrict__ gb1, const float* __restrict__ gb2x,
    float* __restrict__ gxg, int ntiles, int mtiles)
{
    __shared__ __align__(16) float sred[16 * 32 * 20]; // 40 KB
    __shared__ u16 spk[16][33];
    __shared__ __align__(16) u16 gAs[64][40], gBh[64][40], gBl[64][40]; // 15 KB
    const int tid = threadIdx.x;
    const int bid = blockIdx.x;
    const int lane = tid & 63, wv = tid >> 6;
    const int kq = wv >> 1, bh = wv & 1;
    const int fr = lane & 15, kg = lane >> 4;
    const int batch = (bh << 4) + fr;
    const int eb = tid & 31;
    const u32 bko = ((u32)batch << 9) + (kq << 7) + (kg << 3);

    if (bid < NL0) {
        // ================= layer 0: 16 hidden =================
        const int j0 = bid << 4;
        f16x8 Ah_[16];
#pragma unroll
        for (int hq = 0; hq < 4; ++hq) {
            const size_t grow = (((size_t)(fr & 3)) << 9) + j0 + (hq << 2) + (fr >> 2);
#pragma unroll
            for (int ck = 0; ck < 4; ++ck)
                Ah_[(hq << 2) | ck] = *(const f16x8*)(
                    w0h + (grow << 9) + (kq << 7) + (ck << 5) + (kg << 3));
        }
        const int eh = tid >> 5;
        const int hidden = j0 + eh;
        float c_reg = c0ws[((size_t)eb << 9) + hidden];
        __syncthreads();

        for (int jj = 0; jj < Tc; ++jj) {
            const int t = t0 + jj;
            float xv[4];
#pragma unroll
            for (int g = 0; g < 4; ++g)
                xv[g] = xg[(((size_t)eb * Tc + jj) << 11) + (g << 9) + hidden];
            SPIN_WAIT(jj, jj - 6);
            const u16* bp = r0 + (((size_t)((t - 1) & 7)) << 14) + bko;
            f16x8 vb[4];
#pragma unroll
            for (int ck = 0; ck < 4; ++ck)
                LDG16(vb[ck], bp + (ck << 5));
            f32x4 s0[4] = {};
            VMCNT0(); SBAR();
#pragma unroll
            for (int hq = 0; hq < 4; ++hq)
#pragma unroll
                for (int ck = 0; ck < 4; ++ck)
                    s0[hq] = MFMAF(Ah_[(hq << 2) | ck], vb[ck], s0[hq]);
#pragma unroll
            for (int hq = 0; hq < 4; ++hq) {
                const int h16 = (hq << 2) + kg;
                *(f32x4*)&sred[((h16 << 5) + batch) * 20 + (kq << 2)] = s0[hq];
            }
            __syncthreads();
            {
                const int base = ((eh << 5) + eb) * 20;
                const f32x4 q0 = *(const f32x4*)&sred[base];
                const f32x4 q1 = *(const f32x4*)&sred[base + 4];
                const f32x4 q2 = *(const f32x4*)&sred[base + 8];
                const f32x4 q3 = *(const f32x4*)&sred[base + 12];
                const float gi = q0[0] + q1[0] + q2[0] + q3[0] + xv[0];
                const float gf = q0[1] + q1[1] + q2[1] + q3[1] + xv[1];
                const float gg = q0[2] + q1[2] + q2[2] + q3[2] + xv[2];
                const float go = q0[3] + q1[3] + q2[3] + q3[3] + xv[3];
                c_reg = sigf(gf) * c_reg + sigf(gi) * tanhf_(gg);
                const float h = sigf(go) * tanhf_(c_reg);
                spk[eh][eb] = f2h_bits(h);
            }
            __syncthreads();
            if (tid < 128) {
                const int bt = tid & 31, h4 = (tid >> 5) << 2;
                const u64 hp = (u64)spk[h4 + 0][bt] | ((u64)spk[h4 + 1][bt] << 16)
                             | ((u64)spk[h4 + 2][bt] << 32) | ((u64)spk[h4 + 3][bt] << 48);
                const size_t wo = (((size_t)(t & 7)) << 14) + ((size_t)bt << 9) + j0 + h4;
                ST8(r0 + wo, hp);
            }
            VMCNT0();
            __syncthreads();
            if (tid == 0)
                __hip_atomic_store(flags + bid * FSTR, (u32)(jj + 1),
                                   __ATOMIC_RELAXED, __HIP_MEMORY_SCOPE_AGENT);
        }
        c0ws[((size_t)eb << 9) + hidden] = c_reg;
    } else if (bid < NL0 + NL1) {
        // ================= layer 1: 8 hidden =================
        const int j0 = (bid - NL0) << 3;
        f16x8 Ah_[16];
#pragma unroll
        for (int mat = 0; mat < 2; ++mat)
#pragma unroll
            for (int hq = 0; hq < 2; ++hq) {
                const size_t grow = (((size_t)(fr & 3)) << 9) + j0 + (hq << 2) + (fr >> 2);
                const u16* src = mat ? w1hh_h : w1ih_h;
#pragma unroll
                for (int ck = 0; ck < 4; ++ck)
                    Ah_[(((mat << 1) | hq) << 2) | ck] = *(const f16x8*)(
                        src + (grow << 9) + (kq << 7) + (ck << 5) + (kg << 3));
            }
        const int eh = tid >> 5;
        const int hidden = j0 + (eh & 7);
        float bs[4], c_reg = 0.f;
        if (tid < 256) {
#pragma unroll
            for (int g = 0; g < 4; ++g) bs[g] = bsum1[(g << 9) + hidden];
            c_reg = c1ws[((size_t)eb << 9) + hidden];
        }
        __syncthreads();

        for (int jj = 0; jj < NS; ++jj) {
            const int t = t0 + jj - 1;
            SPIN_WAIT(jj, jj);
            if (t >= 0) {
                const u16* ap = r0 + (((size_t)(t & 7)) << 14) + bko;
                const u16* bp = r1 + (((size_t)((t - 1) & 7)) << 14) + bko;
                f16x8 va[4], vb[4];
#pragma unroll
                for (int ck = 0; ck < 4; ++ck) {
                    LDG16(va[ck], ap + (ck << 5));
                    LDG16(vb[ck], bp + (ck << 5));
                }
                f32x4 s0[2] = {};
                VMCNT0(); SBAR();
#pragma unroll
                for (int hq = 0; hq < 2; ++hq)
#pragma unroll
                    for (int ck = 0; ck < 4; ++ck) {
                        const int ia = (hq << 2) | ck;
                        const int ib = ((2 + hq) << 2) | ck;
                        s0[hq] = MFMAF(Ah_[ia], va[ck], s0[hq]);
                        s0[hq] = MFMAF(Ah_[ib], vb[ck], s0[hq]);
                    }
#pragma unroll
                for (int hq = 0; hq < 2; ++hq) {
                    const int h8 = (hq << 2) + kg;
                    *(f32x4*)&sred[((h8 << 5) + batch) * 20 + (kq << 2)] = s0[hq];
                }
            }
            __syncthreads();
            if (t >= 0 && tid < 256) {
                const int base = ((eh << 5) + eb) * 20;
                const f32x4 q0 = *(const f32x4*)&sred[base];
                const f32x4 q1 = *(const f32x4*)&sred[base + 4];
                const f32x4 q2 = *(const f32x4*)&sred[base + 8];
                const f32x4 q3 = *(const f32x4*)&sred[base + 12];
                const float gi = q0[0] + q1[0] + q2[0] + q3[0] + bs[0];
                const float gf = q0[1] + q1[1] + q2[1] + q3[1] + bs[1];
                const float gg = q0[2] + q1[2] + q2[2] + q3[2] + bs[2];
                const float go = q0[3] + q1[3] + q2[3] + q3[3] + bs[3];
                c_reg = sigf(gf) * c_reg + sigf(gi) * tanhf_(gg);
                const float h = sigf(go) * tanhf_(c_reg);
                spk[eh][eb] = f2h_bits(h);
            }
            __syncthreads();
            if (t >= 0 && tid < 64) {
                const int bt = tid & 31, h4 = (tid >> 5) << 2;
                const u64 hp = (u64)spk[h4 + 0][bt] | ((u64)spk[h4 + 1][bt] << 16)
                             | ((u64)spk[h4 + 2][bt] << 32) | ((u64)spk[h4 + 3][bt] << 48);
                const size_t wo = (((size_t)(t & 7)) << 14) + ((size_t)bt << 9) + j0 + h4;
                ST8(r1 + wo, hp);
            }
            VMCNT0();
            __syncthreads();
            if (tid == 0)
                __hip_atomic_store(flags + (bid) * FSTR, (u32)(jj + 1),
                                   __ATOMIC_RELAXED, __HIP_MEMORY_SCOPE_AGENT);
            // out1 write AFTER flag — off the critical path.
            if (t >= 0 && tid < 64) {
                const int bt = tid & 31, h4 = (tid >> 5) << 2;
                float4 o;
                o.x = h2f(spk[h4 + 0][bt]);
                o.y = h2f(spk[h4 + 1][bt]);
                o.z = h2f(spk[h4 + 2][bt]);
                o.w = h2f(spk[h4 + 3][bt]);
                *(float4*)(out1 + (((size_t)bt * T + t) << 9) + j0 + h4) = o;
            }
        }
        if (tid < 256) c1ws[((size_t)eb << 9) + hidden] = c_reg;
    } else {
        // ================= fused next-chunk xg GEMM =================
        const int gb = bid - (NL0 + NL1);
        const int ko = kg << 3;
        for (int tile = gb; tile < ntiles; tile += NGB) {
            const int m0 = (tile % mtiles) << 6;
            const int n0 = (tile / mtiles) << 6;
            const int ar = tid >> 2, aks = (tid & 3) << 3;
            const float* aPtr = nullptr;
            const float* bPtr = nullptr;
            if (tid < 256) {
                const int rg = m0 + ar;
                const int b = rg >> gtc_bits;
                const int tt = gt0 + (rg & ((1 << gtc_bits) - 1));
                aPtr = gA + (((size_t)b * T + tt) << 9) + aks;
                bPtr = gW + (((size_t)(n0 + ar)) << 9) + aks;
            }
            const int wv4 = (tid >> 6) & 3;
            f32x4 acc[4] = {}, accl[4] = {};
            for (int k0 = 0; k0 < HD; k0 += 32) {
                if (tid < 256) {
                    const float4 a1 = *(const float4*)(aPtr + k0);
                    const float4 a2 = *(const float4*)(aPtr + k0 + 4);
                    f16x8 av; cvt8(a1, a2, av);
                    *(f16x8*)&gAs[ar][aks] = av;
                    const float4 w1 = *(const float4*)(bPtr + k0);
                    const float4 w2 = *(const float4*)(bPtr + k0 + 4);
                    f16x8 vh, vl; split8f(w1, w2, vh, vl);
                    *(f16x8*)&gBh[ar][aks] = vh;
                    *(f16x8*)&gBl[ar][aks] = vl;
                }
                __syncthreads();
                if (tid < 256) {
                    const f16x8 ahf = *(const f16x8*)&gAs[(wv4 << 4) + fr][ko];
#pragma unroll
                    for (int nt = 0; nt < 4; ++nt) {
                        const f16x8 bhf = *(const f16x8*)&gBh[(nt << 4) + fr][ko];
                        const f16x8 blf = *(const f16x8*)&gBl[(nt << 4) + fr][ko];
                        acc[nt]  = MFMAF(ahf, bhf, acc[nt]);
                        accl[nt] = MFMAF(ahf, blf, accl[nt]);
                    }
                }
                __syncthreads();
            }
            if (tid < 256) {
                const int mlb = (wv4 << 4) + (kg << 2);
#pragma unroll
                for (int r = 0; r < 4; ++r) {
                    const int mg = m0 + mlb + r;
#pragma unroll
                    for (int nt = 0; nt < 4; ++nt) {
                        const int n = n0 + (nt << 4) + fr;
                        gxg[((size_t)mg << 11) + n] =
                            acc[nt][r] + accl[nt][r] * LOSC + gb1[n] + gb2x[n];
                    }
                }
            }
        }
    }
}

extern "C" void kernel_launch(void* const* d_in, const int* in_sizes, int n_in,
                              void* d_out, int out_size, void* d_ws, size_t ws_size,
                              hipStream_t stream)
{
    const float* x[3]   = {(const float*)d_in[0], (const float*)d_in[1],  (const float*)d_in[2]};
    const float* Wih[3] = {(const float*)d_in[3], (const float*)d_in[9],  (const float*)d_in[15]};
    const float* Whh[3] = {(const float*)d_in[4], (const float*)d_in[10], (const float*)d_in[16]};
    const float* bih[3] = {(const float*)d_in[5], (const float*)d_in[11], (const float*)d_in[17]};
    const float* bhh[3] = {(const float*)d_in[6], (const float*)d_in[12], (const float*)d_in[18]};
    const float* h0[3]  = {(const float*)d_in[7], (const float*)d_in[13], (const float*)d_in[19]};
    const float* c0[3]  = {(const float*)d_in[8], (const float*)d_in[14], (const float*)d_in[20]};
    const float* upW[2] = {(const float*)d_in[21], (const float*)d_in[23]};
    const float* upb[2] = {(const float*)d_in[22], (const float*)d_in[24]};

    float* ws = (float*)d_ws;
    float* bufA  = ws;
    float* bufB  = bufA + (size_t)NB * 256 * HD;
    float* c0ws  = bufB + (size_t)NB * 256 * HD;
    float* c1ws  = c0ws + (size_t)NB * HD;
    float* bsum1 = c1ws + (size_t)NB * HD;
    float* xgA   = bsum1 + GD;

    const size_t head_f = 2 * (size_t)NB * 256 * HD + 2 * (size_t)NB * HD + GD;
    const size_t tail_f = 3 * (size_t)GD * HD + NSLOT * (size_t)NB * HD + 96 * FSTR + 64;
    // double-buffered xg: prefer Tc=512, else 256
    int Tc_cap = 512;
    while (Tc_cap > 32 && (head_f + 2 * (size_t)NB * Tc_cap * GD + tail_f) * 4 > ws_size)
        Tc_cap >>= 1;

    float* xgB  = xgA + (size_t)NB * Tc_cap * GD;
    u16* w0h    = (u16*)(xgB + (size_t)NB * Tc_cap * GD);
    u16* w0l    = w0h + (size_t)GD * HD;
    u16* w1ih_h = w0l + (size_t)GD * HD;
    u16* w1ih_l = w1ih_h + (size_t)GD * HD;
    u16* w1hh_h = w1ih_l + (size_t)GD * HD;
    u16* w1hh_l = w1hh_h + (size_t)GD * HD;
    u16* r0     = w1hh_l + (size_t)GD * HD;   // NSLOT x 16384 u16 (f16 bits)
    u16* r1     = r0 + NSLOT * (size_t)NB * HD;
    u32* flags  = (u32*)(r1 + NSLOT * (size_t)NB * HD);

    auto tier = [&](const float* in, float* out1, int T, int tr) {
        const float* Wih0L = Wih[tr];
        const float* Whh0L = Whh[tr];
        const float* Wih1L = Wih[tr] + (size_t)GD * HD;
        const float* Whh1L = Whh[tr] + (size_t)GD * HD;

        wsplit_kernel<<<(GD * HD) / 256, 256, 0, stream>>>(Whh0L, w0h, w0l, GD * HD);
        wsplit_kernel<<<(GD * HD) / 256, 256, 0, stream>>>(Wih1L, w1ih_h, w1ih_l, GD * HD);
        wsplit_kernel<<<(GD * HD) / 256, 256, 0, stream>>>(Whh1L, w1hh_h, w1hh_l, GD * HD);
        addv_kernel<<<GD / 256, 256, 0, stream>>>(bih[tr] + GD, bhh[tr] + GD, bsum1, GD);
        cvtf_kernel<<<(NB * HD) / 256, 256, 0, stream>>>(
            h0[tr], r0 + 7 * (size_t)NB * HD, NB * HD);
        cvtf_kernel<<<(NB * HD) / 256, 256, 0, stream>>>(
            h0[tr] + (size_t)NB * HD, r1 + 7 * (size_t)NB * HD, NB * HD);
        hipMemcpyAsync(c0ws, c0[tr], (size_t)NB * HD * sizeof(float),
                       hipMemcpyDeviceToDevice, stream);
        hipMemcpyAsync(c1ws, c0[tr] + (size_t)NB * HD, (size_t)NB * HD * sizeof(float),
                       hipMemcpyDeviceToDevice, stream);

        const int Tc = T < Tc_cap ? T : Tc_cap;
        int tc_bits = 0; while ((1 << tc_bits) < Tc) ++tc_bits;
        const int nchunks = T / Tc;
        const int mtiles = (NB * Tc) / 64;
        float* xgb[2] = {xgA, xgB};

        {   // chunk 0 xg: standalone GEMM
            dim3 g(mtiles, GD / 64);
            mfma_gemm<0><<<g, 256, 0, stream>>>(in, T, 0, tc_bits, Wih0L, GD,
                                                bih[tr], bhh[tr], xgb[0], 0, 0);
        }
        for (int ci = 0; ci < nchunks; ++ci) {
            const int t0 = ci * Tc;
            hipMemsetAsync(flags, 0, 96 * FSTR * sizeof(u32), stream);
            const bool last = (ci == nchunks - 1);
            const int NS = Tc + (last ? 1 : 0);
            const int ntiles = last ? 0 : mtiles * (GD / 64);
            const float* xg_p = xgb[ci & 1]; int Tc_a = Tc;
            const u16 *a0 = w0h, *a2 = w1ih_h, *a4 = w1hh_h;
            const float* bs_p = bsum1;
            u16 *p0 = r0, *p1 = r1;
            float *c0p = c0ws, *c1p = c1ws, *o1 = out1;
            int T_a = T, t0_a = t0, NS_a = NS;
            u32* fl = flags;
            const float* gA = in; int gt0 = t0 + Tc; int gtc = tc_bits;
            const float* gW = Wih0L; const float* g1 = bih[tr]; const float* g2 = bhh[tr];
            float* gx = xgb[(ci + 1) & 1]; int nt_a = ntiles; int mt_a = mtiles;
            void* args[] = {(void*)&xg_p, (void*)&Tc_a,
                            (void*)&a0, (void*)&a2, (void*)&a4,
                            (void*)&bs_p, (void*)&p0, (void*)&p1,
                            (void*)&c0p, (void*)&c1p, (void*)&o1,
                            (void*)&T_a, (void*)&t0_a, (void*)&NS_a, (void*)&fl,
                            (void*)&gA, (void*)&gt0, (void*)&gtc,
                            (void*)&gW, (void*)&g1, (void*)&g2,
                            (void*)&gx, (void*)&nt_a, (void*)&mt_a};
            hipLaunchCooperativeKernel((const void*)lstm_scan8f, dim3(256), dim3(512),
                                       args, 0, stream);
        }
    };

    float* dout = (float*)d_out;

    // Tier 0 (T=128): l1 series -> bufB
    tier(x[0], bufB, 128, 0);
    {   // upsample 0: bufB (B,128,512) -> bufA (B,256,512) + x1
        dim3 g((NB * 128) / 64, 1024 / 64);
        mfma_gemm<1><<<g, 256, 0, stream>>>(bufB, 0, 0, 0, upW[0], 1024,
                                            upb[0], x[1], bufA, 7, 1);
    }
    // Tier 1 (T=256): input bufA, l1 series -> bufB
    tier(bufA, bufB, 256, 1);
    {   // upsample 1: bufB (B,256,512) -> dout (B,2048,512) + x2
        dim3 g((NB * 256) / 64, 4096 / 64);
        mfma_gemm<1><<<g, 256, 0, stream>>>(bufB, 0, 0, 0, upW[1], 4096,
                                            upb[1], x[2], dout, 8, 3);
    }
    // Tier 2 (T=2048): input dout (fused GEMM reads chunk i+1 rows; scan writes
    // chunk i rows — disjoint), l1 -> dout
    tier(dout, dout, 2048, 2);
}